// Round 3
// baseline (35533.414 us; speedup 1.0000x reference)
//
#include <hip/hip_runtime.h>
#include <stdint.h>
#include <stddef.h>

// Problem constants (test=False shapes)
#define E_DIM 1024
#define B_SZ  16
#define N_SEQ 1024
#define L_NUM 12
#define ACT_D 640   // DIM*ACT_NUM
#define ADIM_ 10

// ---------------------------------------------------------------------------
// Diagnostic round: all-fp32 vector GEMM (no MFMA, no bf16 anywhere).
// NT GEMM: C[M,N] = A[M,K] @ B[N,K]^T, fp32.
// 64x64 tile, BK=16, 256 threads, each thread 4x4 outputs.
// MODE 0: full grid (blockIdx.x = tm*tilesN + tn), full K
// MODE 1: lower-triangular 64-tiles only (attention S), full K
// MODE 2: full grid, K capped at (tm+1)*64 (S@V causal)
// EPI  0: plain | 2: +bias,relu | 4: relu, causal *1/(row+1) | 5: +bias
// Requires M%64==0, N%64==0, K%16==0, ldc%4==0.
// ---------------------------------------------------------------------------
#define FM 64
#define FN 64
#define FK 16

template<int MODE, int EPI>
__global__ __launch_bounds__(256)
void gemm_nt_f32(const float* __restrict__ A, const float* __restrict__ B,
                 float* __restrict__ C, const float* __restrict__ bias,
                 int K, int lda, int ldb, int ldc, int tilesN,
                 long long sA, long long sB, long long sC)
{
  __shared__ float As[FK][FM + 4];   // [k][m]
  __shared__ float Bs[FK][FN + 4];   // [k][n]

  const int tid = threadIdx.x;
  const int bat = blockIdx.y;
  A += (long long)bat * sA;
  B += (long long)bat * sB;

  int tm, tn;
  if (MODE == 1) {
    int t = blockIdx.x, m = 0;
    while ((m + 1) * (m + 2) / 2 <= t) m++;
    tm = m; tn = t - m * (m + 1) / 2;
  } else {
    tm = blockIdx.x / tilesN;
    tn = blockIdx.x % tilesN;
  }
  int kend = K;
  if (MODE == 2) { int c = (tm + 1) * FM; kend = (c < K) ? c : K; }

  const int tx = tid & 15;        // n-group (4 cols)
  const int ty = tid >> 4;        // m-group (4 rows)
  const int lm = tid >> 2;        // staging row 0..63
  const int lk = (tid & 3) * 4;   // staging k-chunk {0,4,8,12}

  float acc[4][4];
  #pragma unroll
  for (int i = 0; i < 4; i++)
    #pragma unroll
    for (int j = 0; j < 4; j++) acc[i][j] = 0.f;

  for (int k0 = 0; k0 < kend; k0 += FK) {
    const float4 av = *(const float4*)&A[(long long)(tm * FM + lm) * lda + k0 + lk];
    const float4 bv = *(const float4*)&B[(long long)(tn * FN + lm) * ldb + k0 + lk];
    __syncthreads();   // previous iteration's LDS reads complete before overwrite
    As[lk + 0][lm] = av.x; As[lk + 1][lm] = av.y;
    As[lk + 2][lm] = av.z; As[lk + 3][lm] = av.w;
    Bs[lk + 0][lm] = bv.x; Bs[lk + 1][lm] = bv.y;
    Bs[lk + 2][lm] = bv.z; Bs[lk + 3][lm] = bv.w;
    __syncthreads();
    #pragma unroll
    for (int kk = 0; kk < FK; kk++) {
      const float4 a4 = *(const float4*)&As[kk][ty * 4];
      const float4 b4 = *(const float4*)&Bs[kk][tx * 4];
      const float a[4] = {a4.x, a4.y, a4.z, a4.w};
      const float b[4] = {b4.x, b4.y, b4.z, b4.w};
      #pragma unroll
      for (int i = 0; i < 4; i++)
        #pragma unroll
        for (int j = 0; j < 4; j++)
          acc[i][j] = fmaf(a[i], b[j], acc[i][j]);
    }
  }

  #pragma unroll
  for (int i = 0; i < 4; i++) {
    const int grow = tm * FM + ty * 4 + i;
    float ov[4];
    #pragma unroll
    for (int j = 0; j < 4; j++) {
      const int gcol = tn * FN + tx * 4 + j;
      float v = acc[i][j];
      if (EPI == 2)      { v += bias[gcol]; v = v > 0.f ? v : 0.f; }
      else if (EPI == 5) { v += bias[gcol]; }
      else if (EPI == 4) {
        v = v > 0.f ? v : 0.f;
        v = (gcol <= grow) ? v / (float)(grow + 1) : 0.f;
      }
      ov[j] = v;
    }
    *(float4*)&C[(long long)bat * sC + (long long)grow * ldc + tn * FN + tx * 4] =
        *(const float4*)ov;
  }
}

// ---------------------------------------------------------------------------
// Transpose fp32 -> fp32: dst[c][r] = src[r][c]; rows,cols % 32 == 0
// ---------------------------------------------------------------------------
__global__ __launch_bounds__(256)
void transpose_f32(const float* __restrict__ src, float* __restrict__ dst,
                   int rows, int cols)
{
  __shared__ float tile[32][33];
  const int c0 = blockIdx.x * 32, r0 = blockIdx.y * 32;
  const int tx = threadIdx.x & 31, ty = threadIdx.x >> 5;  // 32x8
  #pragma unroll
  for (int i = ty; i < 32; i += 8)
    tile[i][tx] = src[(long long)(r0 + i) * cols + c0 + tx];
  __syncthreads();
  #pragma unroll
  for (int i = ty; i < 32; i += 8)
    dst[(long long)(c0 + i) * rows + r0 + tx] = tile[tx][i];
}

// ---------------------------------------------------------------------------
// Residual add + LayerNorm (all fp32): x = Hs + delta; Hs = LN(x)*g + b
// ---------------------------------------------------------------------------
__global__ __launch_bounds__(256)
void resid_ln(float* __restrict__ Hs, const float* __restrict__ delta,
              const float* __restrict__ g, const float* __restrict__ bta)
{
  __shared__ float red[8];
  const long long row = blockIdx.x;
  float* hp = Hs + row * E_DIM;
  const float* dp = delta + row * E_DIM;
  const int tid = threadIdx.x;
  const int e = tid * 4;

  float4 h = *(const float4*)(hp + e);
  float4 d = *(const float4*)(dp + e);
  float x0 = h.x + d.x, x1 = h.y + d.y, x2 = h.z + d.z, x3 = h.w + d.w;
  float s = x0 + x1 + x2 + x3;
  float q = x0 * x0 + x1 * x1 + x2 * x2 + x3 * x3;
  #pragma unroll
  for (int o = 32; o > 0; o >>= 1) { s += __shfl_down(s, o); q += __shfl_down(q, o); }
  const int lane = tid & 63, wv = tid >> 6;
  if (lane == 0) { red[wv] = s; red[wv + 4] = q; }
  __syncthreads();
  const float st = red[0] + red[1] + red[2] + red[3];
  const float qt = red[4] + red[5] + red[6] + red[7];
  const float mu = st * (1.0f / E_DIM);
  const float var = qt * (1.0f / E_DIM) - mu * mu;
  const float rstd = rsqrtf(var + 1e-5f);

  float4 gg = *(const float4*)(g + e);
  float4 bb = *(const float4*)(bta + e);
  float4 y;
  y.x = (x0 - mu) * rstd * gg.x + bb.x;
  y.y = (x1 - mu) * rstd * gg.y + bb.y;
  y.z = (x2 - mu) * rstd * gg.z + bb.z;
  y.w = (x3 - mu) * rstd * gg.w + bb.w;
  *(float4*)(hp + e) = y;
}

// ---------------------------------------------------------------------------
// Embedding: A_emb[b,e] = act[b,:640] @ W_emb[:640, e]   (b group-local)
// ---------------------------------------------------------------------------
__global__ __launch_bounds__(256)
void emb_dot(const float* __restrict__ act, const float* __restrict__ Wemb,
             float* __restrict__ Aemb)
{
  const int e = blockIdx.x * 256 + threadIdx.x;
  const int b = blockIdx.y;
  const float* ab = act + b * ACT_D;
  float s = 0.f;
  for (int d = 0; d < ACT_D; d++)
    s = fmaf(ab[d], Wemb[(long long)d * E_DIM + e], s);
  Aemb[b * E_DIM + e] = s;
}

// Hs[b,i,:] = (i even ? A_emb[b] : 0) + b_emb + W_emb[651] + (i+1)*W_emb[652] + wpe[i]
__global__ __launch_bounds__(256)
void emb_fill(const float* __restrict__ Aemb, const float* __restrict__ Wemb,
              const float* __restrict__ bemb, const float* __restrict__ wpe,
              float* __restrict__ Hs)
{
  const int i = blockIdx.x, b = blockIdx.y;
  const int e = threadIdx.x * 4;
  float4 a;
  if ((i & 1) == 0) a = *(const float4*)(Aemb + b * E_DIM + e);
  else { a.x = 0.f; a.y = 0.f; a.z = 0.f; a.w = 0.f; }
  float4 be = *(const float4*)(bemb + e);
  float4 w1 = *(const float4*)(Wemb + 651LL * E_DIM + e);
  float4 w2 = *(const float4*)(Wemb + 652LL * E_DIM + e);
  float4 pw = *(const float4*)(wpe + (long long)i * E_DIM + e);
  const float pos = (float)(i + 1);
  float4 y;
  y.x = a.x + be.x + w1.x + pos * w2.x + pw.x;
  y.y = a.y + be.y + w1.y + pos * w2.y + pw.y;
  y.z = a.z + be.z + w1.z + pos * w2.z + pw.z;
  y.w = a.w + be.w + w1.w + pos * w2.w + pw.w;
  *(float4*)(Hs + ((long long)b * N_SEQ + i) * E_DIM + e) = y;
}

// ---------------------------------------------------------------------------
// Final head: out[b,h,:] = Hs[b,2h,:] @ W_pred + b_pred  (b group-local)
// ---------------------------------------------------------------------------
__global__ __launch_bounds__(256)
void pred_k(const float* __restrict__ Hs, const float* __restrict__ Wp,
            const float* __restrict__ bp, float* __restrict__ out)
{
  __shared__ float part[4][ADIM_];
  const int h = blockIdx.x, b = blockIdx.y;
  const long long row = (long long)b * N_SEQ + 2 * h;
  const float* x = Hs + row * E_DIM;
  float acc[ADIM_];
  #pragma unroll
  for (int a = 0; a < ADIM_; a++) acc[a] = 0.f;
  for (int e = threadIdx.x; e < E_DIM; e += 256) {
    const float xv = x[e];
    const float* w = Wp + e * ADIM_;
    #pragma unroll
    for (int a = 0; a < ADIM_; a++) acc[a] = fmaf(xv, w[a], acc[a]);
  }
  const int lane = threadIdx.x & 63, wv = threadIdx.x >> 6;
  #pragma unroll
  for (int a = 0; a < ADIM_; a++)
    #pragma unroll
    for (int o = 32; o > 0; o >>= 1) acc[a] += __shfl_down(acc[a], o);
  if (lane == 0)
    #pragma unroll
    for (int a = 0; a < ADIM_; a++) part[wv][a] = acc[a];
  __syncthreads();
  if (threadIdx.x < ADIM_) {
    const int a = threadIdx.x;
    out[((long long)b * (N_SEQ / 2) + h) * ADIM_ + a] =
        part[0][a] + part[1][a] + part[2][a] + part[3][a] + bp[a];
  }
}

// Diagnostic sentinel: unambiguous "workspace too small" signature
__global__ __launch_bounds__(256)
void fill_sentinel(float* p, int n, float v)
{
  int i = blockIdx.x * 256 + threadIdx.x;
  if (i < n) p[i] = v;
}

// ---------------------------------------------------------------------------
extern "C" void kernel_launch(void* const* d_in, const int* in_sizes, int n_in,
                              void* d_out, int out_size, void* d_ws, size_t ws_size,
                              hipStream_t stream)
{
  const float* act  = (const float*)d_in[0];
  // d_in[1] context_rewards: numerically unused by the reference
  const float* wpe  = (const float*)d_in[2];
  const float* Wemb = (const float*)d_in[3];
  const float* bemb = (const float*)d_in[4];
  const float* Wq   = (const float*)d_in[5];
  const float* Wk   = (const float*)d_in[6];
  const float* Wv   = (const float*)d_in[7];
  const float* ln1g = (const float*)d_in[8];
  const float* ln1b = (const float*)d_in[9];
  const float* W1   = (const float*)d_in[10];
  const float* b1   = (const float*)d_in[11];
  const float* W2   = (const float*)d_in[12];
  const float* b2   = (const float*)d_in[13];
  const float* ln2g = (const float*)d_in[14];
  const float* ln2b = (const float*)d_in[15];
  const float* Wp   = (const float*)d_in[16];
  const float* bp   = (const float*)d_in[17];
  float* out = (float*)d_out;

  const long long sQ = (long long)N_SEQ * E_DIM;   // per-batch activation stride
  const long long sS = (long long)N_SEQ * N_SEQ;   // per-batch score stride

  // fp32 buffers: Hs, q, k, S per batch (4 x 4 MB) + one shared weight buffer
  auto need = [&](int G) -> size_t {
    return (size_t)G * sQ * 16 + (size_t)E_DIM * E_DIM * 4
           + (size_t)G * E_DIM * 4 + 16384;
  };
  int G = 16;
  while (G > 1 && need(G) > ws_size) G >>= 1;
  if (need(G) > ws_size || d_ws == nullptr) {
    fill_sentinel<<<dim3((out_size + 255) / 256), 256, 0, stream>>>(out, out_size, 1.0e7f);
    return;
  }

  char* ws = (char*)d_ws;
  size_t off = 0;
  auto alloc = [&](size_t bytes) -> void* {
    void* p = ws + off;
    off += (bytes + 255) & ~(size_t)255;
    return p;
  };
  float* Hs = (float*)alloc((size_t)G * sQ * 4);
  float* qb = (float*)alloc((size_t)G * sQ * 4);   // q -> vT -> MLP hidden
  float* kb = (float*)alloc((size_t)G * sQ * 4);   // k -> attn delta -> MLP delta
  float* Sb = (float*)alloc((size_t)G * sS * 4);
  float* wt = (float*)alloc((size_t)E_DIM * E_DIM * 4);
  float* Aemb = (float*)alloc((size_t)G * E_DIM * 4);

  const int tilesE = E_DIM / FN;    // 16
  const int tilesS = N_SEQ / FN;    // 16
  const int triS = tilesS * (tilesS + 1) / 2;        // 136
  const dim3 gq((G * N_SEQ / FM) * tilesE, 1);       // folded-batch QKV/MLP grid
  const dim3 gsq(triS, G);                           // triangular S grid
  const dim3 gv(tilesE * tilesS, G);                 // vT / S@V grid
  const dim3 gT(E_DIM / 32, E_DIM / 32);

  for (int g0 = 0; g0 < B_SZ; g0 += G) {
    emb_dot<<<dim3(E_DIM / 256, G), 256, 0, stream>>>(act + (long long)g0 * ACT_D, Wemb, Aemb);
    emb_fill<<<dim3(N_SEQ, G), 256, 0, stream>>>(Aemb, Wemb, bemb, wpe, Hs);

    for (int l = 0; l < L_NUM; l++) {
      const long long wof = (long long)l * E_DIM * E_DIM;

      // q = Hs @ Wq^T (batch folded into M)
      transpose_f32<<<gT, 256, 0, stream>>>(Wq + wof, wt, E_DIM, E_DIM);
      gemm_nt_f32<0, 0><<<gq, 256, 0, stream>>>(Hs, wt, qb, nullptr,
          E_DIM, E_DIM, E_DIM, E_DIM, tilesE, 0, 0, 0);
      // k = Hs @ Wk^T
      transpose_f32<<<gT, 256, 0, stream>>>(Wk + wof, wt, E_DIM, E_DIM);
      gemm_nt_f32<0, 0><<<gq, 256, 0, stream>>>(Hs, wt, kb, nullptr,
          E_DIM, E_DIM, E_DIM, E_DIM, tilesE, 0, 0, 0);

      // S = relu(q k^T) * causal/(i+1), lower-triangular 64-tiles
      gemm_nt_f32<1, 4><<<gsq, 256, 0, stream>>>(qb, kb, Sb, nullptr,
          E_DIM, E_DIM, E_DIM, N_SEQ, tilesS, sQ, sQ, sS);

      // vT[e][j] = sum_k Wv^T[e][k] * Hs[j][k]  (directly transposed v, into qb)
      transpose_f32<<<gT, 256, 0, stream>>>(Wv + wof, wt, E_DIM, E_DIM);
      gemm_nt_f32<0, 0><<<gv, 256, 0, stream>>>(wt, Hs, qb, nullptr,
          E_DIM, E_DIM, E_DIM, N_SEQ, tilesS, 0, sQ, sQ);

      // attn delta = S @ v (K capped at diagonal), into kb
      gemm_nt_f32<2, 0><<<gv, 256, 0, stream>>>(Sb, qb, kb, nullptr,
          N_SEQ, N_SEQ, N_SEQ, E_DIM, tilesE, sS, sQ, sQ);

      // Hs = LN1(Hs + delta)
      resid_ln<<<dim3(G * N_SEQ), 256, 0, stream>>>(Hs, kb,
          ln1g + (long long)l * E_DIM, ln1b + (long long)l * E_DIM);

      // MLP: hidden = relu(Hs@W1^T + b1) -> qb ; delta = hidden@W2^T + b2 -> kb
      transpose_f32<<<gT, 256, 0, stream>>>(W1 + wof, wt, E_DIM, E_DIM);
      gemm_nt_f32<0, 2><<<gq, 256, 0, stream>>>(Hs, wt, qb, b1 + (long long)l * E_DIM,
          E_DIM, E_DIM, E_DIM, E_DIM, tilesE, 0, 0, 0);
      transpose_f32<<<gT, 256, 0, stream>>>(W2 + wof, wt, E_DIM, E_DIM);
      gemm_nt_f32<0, 5><<<gq, 256, 0, stream>>>(qb, wt, kb, b2 + (long long)l * E_DIM,
          E_DIM, E_DIM, E_DIM, E_DIM, tilesE, 0, 0, 0);

      // Hs = LN2(Hs + delta)
      resid_ln<<<dim3(G * N_SEQ), 256, 0, stream>>>(Hs, kb,
          ln2g + (long long)l * E_DIM, ln2b + (long long)l * E_DIM);
    }

    pred_k<<<dim3(N_SEQ / 2, G), 256, 0, stream>>>(Hs, Wp, bp,
        out + (long long)g0 * (N_SEQ / 2) * ADIM_);
  }
}